// Round 4
// baseline (1036.902 us; speedup 1.0000x reference)
//
#include <hip/hip_runtime.h>
#include <hip/hip_bf16.h>

typedef __attribute__((ext_vector_type(8))) __bf16 bf16x8;
typedef __attribute__((ext_vector_type(4))) float f32x4;
typedef __attribute__((ext_vector_type(4))) unsigned short u16x4;

#define NN 50000
#define GNODES 8   // nodes per block, k_global (6250 blocks)
#define PNODES 8   // nodes per block, k_points -> 64 point rows (6250 blocks)

// ws layout (u16 elements):
//   0        : W0t bf16 [256 n][320 k]   (81920)
//   81920    : W1t bf16 [256 n][256 k]   (65536)
//   147456   : W2t bf16 [256 n][256 k]   (65536)
//   212992   : feats bf16 [50000][64]    (3,200,000)
//   3412992  : global split weights (bf16 hi/lo), 106496 elts
#define FEATS_OFF 212992
#define GW_OFF    3412992

__device__ __forceinline__ unsigned short f2bf(float f) {
    unsigned int u = __builtin_bit_cast(unsigned int, f);
    u = (u + 0x7FFFu + ((u >> 16) & 1u)) >> 16;   // RNE; inputs are finite
    return (unsigned short)u;
}
__device__ __forceinline__ float bf2f(unsigned short h) {
    return __builtin_bit_cast(float, (unsigned int)h << 16);
}

// ---------------------------------------------------------------------------
// Prep: point-MLP weights -> bf16 transposed; global-MLP weights -> split
// bf16 hi/lo transposed (fp32-grade MFMA via A_h*W_h + A_l*W_h + A_h*W_l)
// ---------------------------------------------------------------------------
__global__ __launch_bounds__(256) void k_prep(
    const float* __restrict__ W0, const float* __restrict__ W1,
    const float* __restrict__ W2,
    const float* __restrict__ Wg0, const float* __restrict__ Wg1,
    const float* __restrict__ Wg2,
    unsigned short* __restrict__ wbf)
{
    int idx = blockIdx.x * 256 + threadIdx.x;
    if (idx < 81920) {                       // W0t[n][k] = W0[k][n], k<320
        int n = idx / 320, k = idx - n * 320;
        wbf[idx] = f2bf(W0[(size_t)k * 256 + n]);
    } else if (idx < 147456) {               // W1t
        int e = idx - 81920;
        int n = e >> 8, k = e & 255;
        wbf[idx] = f2bf(W1[(size_t)k * 256 + n]);
    } else if (idx < 212992) {               // W2t
        int e = idx - 147456;
        int n = e >> 8, k = e & 255;
        wbf[idx] = f2bf(W2[(size_t)k * 256 + n]);
    } else if (idx < 319488) {               // global weights, split hi/lo
        int e = idx - 212992;                // 0 .. 106495
        float v; int oh, ol;
        if (e < 65536) {                     // Wg0t [256][256]
            int n = e >> 8, k = e & 255;
            v = Wg0[(size_t)k * 256 + n];
            oh = GW_OFF + e; ol = GW_OFF + 65536 + e;
        } else if (e < 98304) {              // Wg1t [128][256]
            int e2 = e - 65536;
            int n = e2 >> 8, k = e2 & 255;
            v = Wg1[(size_t)k * 128 + n];
            oh = GW_OFF + 131072 + e2; ol = GW_OFF + 163840 + e2;
        } else {                             // Wg2t [64][128]
            int e3 = e - 98304;
            int n = e3 >> 7, k = e3 & 127;
            v = Wg2[(size_t)k * 64 + n];
            oh = GW_OFF + 196608 + e3; ol = GW_OFF + 204800 + e3;
        }
        unsigned short h = f2bf(v);
        wbf[oh] = h;
        wbf[ol] = f2bf(v - bf2f(h));
    }
}

// ---------------------------------------------------------------------------
// Kernel 1: global feature MLP (split-bf16 MFMA) + decoder head + cluster
// 8 nodes/block, 256 threads, LDS 18.9 KB -> 6 blocks/CU (24 waves/CU)
//
// smem: xh@0 [8][264]u16 (4224) | xl@4224 | gh@8448 | gl@12672
//       q1h@0 [8][136] (2176, alias: xh dead) | q1l@2176
//       g2@16896 f32[8][64] (2048)                       total 18944 B
// ---------------------------------------------------------------------------
__global__ __launch_bounds__(256, 6) void k_global(
    const float* __restrict__ x,
    const float* __restrict__ bg0, const float* __restrict__ bg1,
    const float* __restrict__ bg2,
    const float* __restrict__ Wdec, const float* __restrict__ bdec,
    const unsigned short* __restrict__ gw,
    unsigned short* __restrict__ feats_bf,
    float* __restrict__ out_rel,
    float* __restrict__ out_cluster)
{
    __shared__ __attribute__((aligned(16))) unsigned char smem[18944];
    unsigned short* xh  = (unsigned short*)(smem);
    unsigned short* xl  = (unsigned short*)(smem + 4224);
    unsigned short* q1h = (unsigned short*)(smem);          // alias (xh dead)
    unsigned short* q1l = (unsigned short*)(smem + 2176);
    unsigned short* gh  = (unsigned short*)(smem + 8448);
    unsigned short* gl  = (unsigned short*)(smem + 12672);
    float*          g2  = (float*)(smem + 16896);

    const int tid  = threadIdx.x;
    const int lane = tid & 63;
    const int w    = tid >> 6;      // wave id 0..3
    const int quad = lane >> 4;     // 0..3
    const int l15  = lane & 15;
    const int blk  = blockIdx.x;
    const size_t nb = (size_t)blk * GNODES;

    // ---- stage 8 node rows, split fp32 -> bf16 hi + lo (float4 loads)
    {
        const float4* xg = (const float4*)(x + nb * 256);
        #pragma unroll
        for (int it = 0; it < 2; ++it) {
            int e = tid + it * 256;          // 512 float4 total
            int r = e >> 6, c4 = e & 63;
            float4 v = xg[e];
            u16x4 hv, lv;
            hv[0] = f2bf(v.x); lv[0] = f2bf(v.x - bf2f(hv[0]));
            hv[1] = f2bf(v.y); lv[1] = f2bf(v.y - bf2f(hv[1]));
            hv[2] = f2bf(v.z); lv[2] = f2bf(v.z - bf2f(hv[2]));
            hv[3] = f2bf(v.w); lv[3] = f2bf(v.w - bf2f(hv[3]));
            *(u16x4*)&xh[r * 264 + c4 * 4] = hv;
            *(u16x4*)&xl[r * 264 + c4 * 4] = lv;
        }
    }
    __syncthreads();   // B1

    // ---- L0: 256 -> 256 (rows dup 8->16, drop top)
    {
        const unsigned short* Wh = gw;
        const unsigned short* Wl = gw + 65536;
        f32x4 acc[4];
        f32x4 z = {0.f, 0.f, 0.f, 0.f};
        #pragma unroll
        for (int t = 0; t < 4; ++t) acc[t] = z;
        const int ar = (l15 & 7) * 264;
        for (int ks = 0; ks < 8; ++ks) {
            int k0 = ks * 32 + quad * 8;
            bf16x8 ah = *(const bf16x8*)&xh[ar + k0];
            bf16x8 al = *(const bf16x8*)&xl[ar + k0];
            #pragma unroll
            for (int t = 0; t < 4; ++t) {
                int n = w * 64 + t * 16 + l15;
                bf16x8 bh = *(const bf16x8*)(Wh + (size_t)n * 256 + k0);
                bf16x8 bl = *(const bf16x8*)(Wl + (size_t)n * 256 + k0);
                acc[t] = __builtin_amdgcn_mfma_f32_16x16x32_bf16(ah, bh, acc[t], 0, 0, 0);
                acc[t] = __builtin_amdgcn_mfma_f32_16x16x32_bf16(al, bh, acc[t], 0, 0, 0);
                acc[t] = __builtin_amdgcn_mfma_f32_16x16x32_bf16(ah, bl, acc[t], 0, 0, 0);
            }
        }
        #pragma unroll
        for (int t = 0; t < 4; ++t) {
            int col = w * 64 + t * 16 + l15;
            float bb = bg0[col];
            #pragma unroll
            for (int r = 0; r < 4; ++r) {
                int row = quad * 4 + r;
                if (row < 8) {
                    float v = fmaxf(acc[t][r] + bb, 0.f);
                    unsigned short hv = f2bf(v);
                    gh[row * 264 + col] = hv;
                    gl[row * 264 + col] = f2bf(v - bf2f(hv));
                }
            }
        }
    }
    __syncthreads();   // B2 (xh/xl dead; q1 may alias)

    // ---- L1: 256 -> 128
    {
        const unsigned short* Wh = gw + 131072;
        const unsigned short* Wl = gw + 163840;
        f32x4 acc[2];
        f32x4 z = {0.f, 0.f, 0.f, 0.f};
        acc[0] = z; acc[1] = z;
        const int ar = (l15 & 7) * 264;
        for (int ks = 0; ks < 8; ++ks) {
            int k0 = ks * 32 + quad * 8;
            bf16x8 ah = *(const bf16x8*)&gh[ar + k0];
            bf16x8 al = *(const bf16x8*)&gl[ar + k0];
            #pragma unroll
            for (int t = 0; t < 2; ++t) {
                int n = w * 32 + t * 16 + l15;
                bf16x8 bh = *(const bf16x8*)(Wh + (size_t)n * 256 + k0);
                bf16x8 bl = *(const bf16x8*)(Wl + (size_t)n * 256 + k0);
                acc[t] = __builtin_amdgcn_mfma_f32_16x16x32_bf16(ah, bh, acc[t], 0, 0, 0);
                acc[t] = __builtin_amdgcn_mfma_f32_16x16x32_bf16(al, bh, acc[t], 0, 0, 0);
                acc[t] = __builtin_amdgcn_mfma_f32_16x16x32_bf16(ah, bl, acc[t], 0, 0, 0);
            }
        }
        #pragma unroll
        for (int t = 0; t < 2; ++t) {
            int col = w * 32 + t * 16 + l15;
            float bb = bg1[col];
            #pragma unroll
            for (int r = 0; r < 4; ++r) {
                int row = quad * 4 + r;
                if (row < 8) {
                    float v = fmaxf(acc[t][r] + bb, 0.f);
                    unsigned short hv = f2bf(v);
                    q1h[row * 136 + col] = hv;
                    q1l[row * 136 + col] = f2bf(v - bf2f(hv));
                }
            }
        }
    }
    __syncthreads();   // B3

    // ---- L2: 128 -> 64 ; emit g2 (fp32)
    {
        const unsigned short* Wh = gw + 196608;
        const unsigned short* Wl = gw + 204800;
        f32x4 acc = {0.f, 0.f, 0.f, 0.f};
        const int ar = (l15 & 7) * 136;
        for (int ks = 0; ks < 4; ++ks) {
            int k0 = ks * 32 + quad * 8;
            bf16x8 ah = *(const bf16x8*)&q1h[ar + k0];
            bf16x8 al = *(const bf16x8*)&q1l[ar + k0];
            int n = w * 16 + l15;
            bf16x8 bh = *(const bf16x8*)(Wh + (size_t)n * 128 + k0);
            bf16x8 bl = *(const bf16x8*)(Wl + (size_t)n * 128 + k0);
            acc = __builtin_amdgcn_mfma_f32_16x16x32_bf16(ah, bh, acc, 0, 0, 0);
            acc = __builtin_amdgcn_mfma_f32_16x16x32_bf16(al, bh, acc, 0, 0, 0);
            acc = __builtin_amdgcn_mfma_f32_16x16x32_bf16(ah, bl, acc, 0, 0, 0);
        }
        int col = w * 16 + l15;
        float bb = bg2[col];
        #pragma unroll
        for (int r = 0; r < 4; ++r) {
            int row = quad * 4 + r;
            if (row < 8) g2[row * 64 + col] = fmaxf(acc[r] + bb, 0.f);
        }
    }
    __syncthreads();   // B4

    // ---- feats -> ws as bf16 (512 elts)
    if (tid < 128) {
        const float* src = g2 + tid * 4;
        u16x4 p;
        p[0] = f2bf(src[0]); p[1] = f2bf(src[1]);
        p[2] = f2bf(src[2]); p[3] = f2bf(src[3]);
        *(u16x4*)&feats_bf[(size_t)blk * 512 + tid * 4] = p;
    }

    // ---- decoder head: 8 nodes x 24 outputs, fp32
    if (tid < 192) {
        int m = tid / 24, c = tid - m * 24;
        float acc = bdec[c];
        for (int i = 0; i < 64; ++i) acc += g2[m * 64 + i] * Wdec[i * 24 + c];
        out_rel[(size_t)blk * 192 + tid] = acc;
    }

    // ---- cluster ids: 64 point rows per block
    if (tid < 64)
        out_cluster[(size_t)blk * 64 + tid] = (float)(blk * 8 + (tid >> 3));
}

// ---------------------------------------------------------------------------
// Kernel 2: per-point MLP via bf16 MFMA, rank-3 fused concat
// 8 nodes = 64 rows/block, 256 threads (4 waves = 4 col groups), 6250 blocks
// LDS 36.6 KB -> 4 blocks/CU (16 waves/CU, 4 independent chains)
//
// smem: hB [64][256] bf16 XOR-swz @0 (32768)
//         xcat [8][336]u16 alias @0 (5376, dead after L0)
//         sp f32[8][256] alias @24576 (reads pre-staged to regs before
//         h writes -> no race)
//       w3 f32[3][256] @32768 (3072) | rl f32[8][24] @35840 (768)
// ---------------------------------------------------------------------------
__global__ __launch_bounds__(256, 4) void k_points(
    const float* __restrict__ x,
    const unsigned short* __restrict__ feats_bf,
    const float* __restrict__ rel_in,
    const unsigned short* __restrict__ wbf,
    const float* __restrict__ W0f,       // fp32 W0, rows 320..322 (rel cols)
    const float* __restrict__ b0,
    const float* __restrict__ b1,
    const float* __restrict__ b2,
    float* __restrict__ out_dec)
{
    __shared__ __attribute__((aligned(16))) unsigned char smem[36608];
    unsigned char*  hB   = smem;
    unsigned short* xcat = (unsigned short*)smem;             // [8][336]
    float*          sp   = (float*)(smem + 24576);            // [8][256]
    float*          w3   = (float*)(smem + 32768);            // [3][256]
    float*          rl   = (float*)(smem + 35840);            // [8][24]

    const int tid  = threadIdx.x;
    const int lane = tid & 63;
    const int w    = tid >> 6;      // wave id 0..3 -> cols [64w, 64w+64)
    const int quad = lane >> 4;
    const int l15  = lane & 15;
    const int blk  = blockIdx.x;
    const size_t nb = (size_t)blk * PNODES;

    // ---- P0: stage x (bf16), feats (bf16 copy), w3, rl
    {
        const float4* xg = (const float4*)(x + nb * 256);
        #pragma unroll
        for (int it = 0; it < 2; ++it) {
            int e = tid + it * 256;          // 512 float4 total
            int r = e >> 6, c4 = e & 63;
            float4 v = xg[e];
            u16x4 hv;
            hv[0] = f2bf(v.x); hv[1] = f2bf(v.y);
            hv[2] = f2bf(v.z); hv[3] = f2bf(v.w);
            *(u16x4*)&xcat[r * 336 + c4 * 4] = hv;
        }
        {   // feats: 512 u16 = 256 u32, one per thread
            int e = tid * 2;
            int r = e >> 6, c = e & 63;
            *(unsigned int*)&xcat[r * 336 + 256 + c] =
                *(const unsigned int*)&feats_bf[nb * 64 + e];
        }
        for (int e = tid; e < 768; e += 256)
            w3[e] = W0f[(size_t)(320 + (e >> 8)) * 256 + (e & 255)];
        if (tid < 192) rl[tid] = rel_in[nb * 24 + tid];
    }
    __syncthreads();   // B1

    // ---- P1: point L0 [8(dup16) x 320] @ W0t -> sp (pre-relu, pre-rel)
    {
        const unsigned short* W0t = wbf;                    // [256 n][320 k]
        f32x4 acc[4];
        f32x4 z = {0.f, 0.f, 0.f, 0.f};
        #pragma unroll
        for (int t = 0; t < 4; ++t) acc[t] = z;
        const int ar = (lane & 7) * 336;
        for (int ks = 0; ks < 10; ++ks) {
            int k0 = ks * 32 + quad * 8;
            bf16x8 a = *(const bf16x8*)&xcat[ar + k0];
            #pragma unroll
            for (int t = 0; t < 4; ++t) {
                int n = w * 64 + t * 16 + l15;
                bf16x8 b = *(const bf16x8*)(W0t + (size_t)n * 320 + k0);
                acc[t] = __builtin_amdgcn_mfma_f32_16x16x32_bf16(a, b, acc[t], 0, 0, 0);
            }
        }
        #pragma unroll
        for (int t = 0; t < 4; ++t) {
            int col = w * 64 + t * 16 + l15;
            float bb = b0[col];
            #pragma unroll
            for (int r = 0; r < 4; ++r) {
                int row = quad * 4 + r;
                if (row < 8) sp[row * 256 + col] = acc[t][r] + bb;
            }
        }
    }
    __syncthreads();   // B2: sp complete; xcat dead

    // ---- P2: expand sp -> h[64][256] bf16 swz, rank-3 rel + relu
    //      wave w owns rows [16w,16w+16) = nodes 2w, 2w+1
    {
        float4 sv0 = *(const float4*)&sp[(2 * w) * 256 + lane * 4];
        float4 sv1 = *(const float4*)&sp[(2 * w + 1) * 256 + lane * 4];
        float4 wa  = *(const float4*)&w3[lane * 4];
        float4 wb4 = *(const float4*)&w3[256 + lane * 4];
        float4 wc4 = *(const float4*)&w3[512 + lane * 4];
        __syncthreads();   // B3: all sp reads in regs; h writes may begin
        #pragma unroll
        for (int it = 0; it < 16; ++it) {
            int row  = w * 16 + it;
            int node = 2 * w + (it >> 3);
            int p    = it & 7;
            float4 sv = (it < 8) ? sv0 : sv1;
            float ra = rl[node * 24 + p * 3 + 0];
            float rb = rl[node * 24 + p * 3 + 1];
            float rc = rl[node * 24 + p * 3 + 2];
            float v0 = fmaxf(sv.x + ra * wa.x + rb * wb4.x + rc * wc4.x, 0.f);
            float v1 = fmaxf(sv.y + ra * wa.y + rb * wb4.y + rc * wc4.y, 0.f);
            float v2 = fmaxf(sv.z + ra * wa.z + rb * wb4.z + rc * wc4.z, 0.f);
            float v3 = fmaxf(sv.w + ra * wa.w + rb * wb4.w + rc * wc4.w, 0.f);
            unsigned int lo = (unsigned int)f2bf(v0) | ((unsigned int)f2bf(v1) << 16);
            unsigned int hi = (unsigned int)f2bf(v2) | ((unsigned int)f2bf(v3) << 16);
            uint2 pk; pk.x = lo; pk.y = hi;
            int byteoff = row * 512 +
                ((((lane >> 1) ^ (row & 7)) << 4) | ((lane & 1) << 3));
            *(uint2*)(hB + byteoff) = pk;
        }
    }
    __syncthreads();   // B4

    // ---- FC1: h1 = relu(h0 @ W1 + b1); h1 overwrites h0 (reg-buffered)
    {
        const unsigned short* W1t = wbf + 81920;            // [256 n][256 k]
        f32x4 acc[4][4];
        f32x4 z = {0.f, 0.f, 0.f, 0.f};
        #pragma unroll
        for (int m = 0; m < 4; ++m)
            #pragma unroll
            for (int t = 0; t < 4; ++t) acc[m][t] = z;
        for (int ks = 0; ks < 8; ++ks) {
            int k0 = ks * 32 + quad * 8;
            int g  = k0 >> 3;
            bf16x8 a[4], b[4];
            #pragma unroll
            for (int m = 0; m < 4; ++m) {
                int row = m * 16 + l15;
                a[m] = *(const bf16x8*)(hB + row * 512 + ((g ^ (row & 7)) << 4));
            }
            #pragma unroll
            for (int t = 0; t < 4; ++t)
                b[t] = *(const bf16x8*)(W1t + (size_t)(w * 64 + t * 16 + l15) * 256 + k0);
            #pragma unroll
            for (int m = 0; m < 4; ++m)
                #pragma unroll
                for (int t = 0; t < 4; ++t)
                    acc[m][t] = __builtin_amdgcn_mfma_f32_16x16x32_bf16(a[m], b[t], acc[m][t], 0, 0, 0);
        }
        __syncthreads();   // B5: all h0 reads complete before overwrite
        #pragma unroll
        for (int t = 0; t < 4; ++t) {
            int col = w * 64 + t * 16 + l15;
            float bb = b1[col];
            #pragma unroll
            for (int m = 0; m < 4; ++m) {
                #pragma unroll
                for (int r = 0; r < 4; ++r) {
                    int row = m * 16 + quad * 4 + r;
                    int byteoff = row * 512 +
                        ((((col >> 3) ^ (row & 7)) << 4) | ((col & 7) << 1));
                    *(unsigned short*)(hB + byteoff) =
                        f2bf(fmaxf(acc[m][t][r] + bb, 0.f));
                }
            }
        }
    }
    __syncthreads();   // B6

    // ---- FC2: out = relu(h1 @ W2 + b2) -> staged wave-local -> float4 out
    {
        const unsigned short* W2t = wbf + 147456;
        f32x4 acc[4][4];
        f32x4 z = {0.f, 0.f, 0.f, 0.f};
        #pragma unroll
        for (int m = 0; m < 4; ++m)
            #pragma unroll
            for (int t = 0; t < 4; ++t) acc[m][t] = z;
        for (int ks = 0; ks < 8; ++ks) {
            int k0 = ks * 32 + quad * 8;
            int g  = k0 >> 3;
            bf16x8 a[4], b[4];
            #pragma unroll
            for (int m = 0; m < 4; ++m) {
                int row = m * 16 + l15;
                a[m] = *(const bf16x8*)(hB + row * 512 + ((g ^ (row & 7)) << 4));
            }
            #pragma unroll
            for (int t = 0; t < 4; ++t)
                b[t] = *(const bf16x8*)(W2t + (size_t)(w * 64 + t * 16 + l15) * 256 + k0);
            #pragma unroll
            for (int m = 0; m < 4; ++m)
                #pragma unroll
                for (int t = 0; t < 4; ++t)
                    acc[m][t] = __builtin_amdgcn_mfma_f32_16x16x32_bf16(a[m], b[t], acc[m][t], 0, 0, 0);
        }
        __syncthreads();   // B7: all h1 reads complete; hB reusable as stage

        // wave-local transpose through hB + w*8192 ([32][64] f32, bank-XOR)
        float* ofw = (float*)(hB + (size_t)w * 8192);
        float bb[4];
        #pragma unroll
        for (int t = 0; t < 4; ++t) bb[t] = b2[w * 64 + t * 16 + l15];
        #pragma unroll
        for (int half = 0; half < 2; ++half) {
            #pragma unroll
            for (int mm = 0; mm < 2; ++mm) {
                int m = half * 2 + mm;
                #pragma unroll
                for (int t = 0; t < 4; ++t) {
                    int c = t * 16 + l15;
                    int csw = c ^ (quad << 3);
                    #pragma unroll
                    for (int r = 0; r < 4; ++r) {
                        int rloc = mm * 16 + quad * 4 + r;
                        ofw[rloc * 64 + csw] = fmaxf(acc[m][t][r] + bb[t], 0.f);
                    }
                }
            }
            // same-wave LDS ops are in-order; compiler sees alias via ofw
            #pragma unroll
            for (int i = 0; i < 8; ++i) {
                int e = lane + i * 64;          // float4 idx 0..511
                int rloc = e >> 4, gc = e & 15;
                f32x4 v = *(const f32x4*)&ofw[rloc * 64 +
                    ((gc * 4) ^ ((((rloc >> 2) & 3)) << 3))];
                int row = half * 32 + rloc;
                *(f32x4*)&out_dec[((size_t)blk * 64 + row) * 256 +
                                  w * 64 + gc * 4] = v;
            }
        }
    }
}

// ---------------------------------------------------------------------------
extern "C" void kernel_launch(void* const* d_in, const int* in_sizes, int n_in,
                              void* d_out, int out_size, void* d_ws, size_t ws_size,
                              hipStream_t stream) {
    const float* x    = (const float*)d_in[0];
    const float* Wg0  = (const float*)d_in[1];
    const float* bg0  = (const float*)d_in[2];
    const float* Wg1  = (const float*)d_in[3];
    const float* bg1  = (const float*)d_in[4];
    const float* Wg2  = (const float*)d_in[5];
    const float* bg2  = (const float*)d_in[6];
    const float* Wdec = (const float*)d_in[7];
    const float* bdec = (const float*)d_in[8];
    const float* W0   = (const float*)d_in[9];
    const float* b0   = (const float*)d_in[10];
    const float* W1   = (const float*)d_in[11];
    const float* b1   = (const float*)d_in[12];
    const float* W2   = (const float*)d_in[13];
    const float* b2   = (const float*)d_in[14];

    float* out      = (float*)d_out;
    float* out_rel  = out;                         // [400000, 3]
    float* out_dec  = out + 1200000;               // [400000, 256]
    float* out_clu  = out + 103600000;             // [400000] as float

    unsigned short* wbf      = (unsigned short*)d_ws;
    unsigned short* feats_bf = wbf + FEATS_OFF;    // [50000, 64] bf16
    unsigned short* gw       = wbf + GW_OFF;       // split global weights

    k_prep<<<1248, 256, 0, stream>>>(W0, W1, W2, Wg0, Wg1, Wg2, wbf);
    k_global<<<NN / GNODES, 256, 0, stream>>>(x, bg0, bg1, bg2, Wdec, bdec, gw,
                                              feats_bf, out_rel, out_clu);
    k_points<<<NN / PNODES, 256, 0, stream>>>(x, feats_bf, out_rel,
                                              wbf, W0, b0, b1, b2, out_dec);
}

// Round 5
// 876.453 us; speedup vs baseline: 1.1831x; 1.1831x over previous
//
#include <hip/hip_runtime.h>
#include <hip/hip_bf16.h>

typedef __attribute__((ext_vector_type(8))) __bf16 bf16x8;
typedef __attribute__((ext_vector_type(4))) float f32x4;
typedef __attribute__((ext_vector_type(4))) unsigned short u16x4;

#define NN 50000
#define TM1 16     // nodes per block, k_global (3125 blocks)
#define PNODES 16  // nodes per block, k_points -> 128 point rows (3125 blocks)

// ws layout (u16 elements):
//   0        : W0t bf16 [256 n][320 k]   (81920)
//   81920    : W1t bf16 [256 n][256 k]   (65536)
//   147456   : W2t bf16 [256 n][256 k]   (65536)
//   212992   : feats bf16 [50000][64]    (3,200,000)
//   3412992  : global split weights (bf16 hi/lo), 106496 elts
#define FEATS_OFF 212992
#define GW_OFF    3412992

__device__ __forceinline__ unsigned short f2bf(float f) {
    unsigned int u = __builtin_bit_cast(unsigned int, f);
    u = (u + 0x7FFFu + ((u >> 16) & 1u)) >> 16;   // RNE; inputs are finite
    return (unsigned short)u;
}
__device__ __forceinline__ float bf2f(unsigned short h) {
    return __builtin_bit_cast(float, (unsigned int)h << 16);
}

// ---------------------------------------------------------------------------
// Prep: point-MLP weights -> bf16 transposed; global-MLP weights -> split
// bf16 hi/lo transposed (fp32-grade MFMA via A_h*W_h + A_l*W_h + A_h*W_l)
// ---------------------------------------------------------------------------
__global__ __launch_bounds__(256) void k_prep(
    const float* __restrict__ W0, const float* __restrict__ W1,
    const float* __restrict__ W2,
    const float* __restrict__ Wg0, const float* __restrict__ Wg1,
    const float* __restrict__ Wg2,
    unsigned short* __restrict__ wbf)
{
    int idx = blockIdx.x * 256 + threadIdx.x;
    if (idx < 81920) {                       // W0t[n][k] = W0[k][n], k<320
        int n = idx / 320, k = idx - n * 320;
        wbf[idx] = f2bf(W0[(size_t)k * 256 + n]);
    } else if (idx < 147456) {               // W1t
        int e = idx - 81920;
        int n = e >> 8, k = e & 255;
        wbf[idx] = f2bf(W1[(size_t)k * 256 + n]);
    } else if (idx < 212992) {               // W2t
        int e = idx - 147456;
        int n = e >> 8, k = e & 255;
        wbf[idx] = f2bf(W2[(size_t)k * 256 + n]);
    } else if (idx < 319488) {               // global weights, split hi/lo
        int e = idx - 212992;                // 0 .. 106495
        float v; int oh, ol;
        if (e < 65536) {                     // Wg0t [256][256]
            int n = e >> 8, k = e & 255;
            v = Wg0[(size_t)k * 256 + n];
            oh = GW_OFF + e; ol = GW_OFF + 65536 + e;
        } else if (e < 98304) {              // Wg1t [128][256]
            int e2 = e - 65536;
            int n = e2 >> 8, k = e2 & 255;
            v = Wg1[(size_t)k * 128 + n];
            oh = GW_OFF + 131072 + e2; ol = GW_OFF + 163840 + e2;
        } else {                             // Wg2t [64][128]
            int e3 = e - 98304;
            int n = e3 >> 7, k = e3 & 127;
            v = Wg2[(size_t)k * 64 + n];
            oh = GW_OFF + 196608 + e3; ol = GW_OFF + 204800 + e3;
        }
        unsigned short h = f2bf(v);
        wbf[oh] = h;
        wbf[ol] = f2bf(v - bf2f(h));
    }
}

// ---------------------------------------------------------------------------
// Kernel 1: global feature MLP (split-bf16 MFMA) + decoder head + cluster
// 16 nodes/block, 256 threads, LDS 25.6 KB -> 6 blocks/CU (24 waves/CU)
//
// smem regions (all lifetime transitions barrier-separated):
//   A @0     [16][264]u16 (8448): xh  -> hh   (L0 epilogue reg-held)
//   B @8448  [16][264]u16 (8448): xl  -> hl
//   C @16896 (8704): q1h@16896 + q1l@21248 -> g2 f32[16][64]@16896
//                                              (L2 epilogue reg-held)
// ---------------------------------------------------------------------------
__global__ __launch_bounds__(256, 6) void k_global(
    const float* __restrict__ x,
    const float* __restrict__ bg0, const float* __restrict__ bg1,
    const float* __restrict__ bg2,
    const float* __restrict__ Wdec, const float* __restrict__ bdec,
    const unsigned short* __restrict__ gw,
    unsigned short* __restrict__ feats_bf,
    float* __restrict__ out_rel,
    float* __restrict__ out_cluster)
{
    __shared__ __attribute__((aligned(16))) unsigned char smem[25600];
    unsigned short* bufA = (unsigned short*)(smem);           // xh -> hh
    unsigned short* bufB = (unsigned short*)(smem + 8448);    // xl -> hl
    unsigned short* q1h  = (unsigned short*)(smem + 16896);
    unsigned short* q1l  = (unsigned short*)(smem + 21248);
    float*          g2   = (float*)(smem + 16896);            // after q1 dead

    const int tid  = threadIdx.x;
    const int lane = tid & 63;
    const int w    = tid >> 6;      // wave id 0..3
    const int quad = lane >> 4;     // 0..3
    const int l15  = lane & 15;
    const int blk  = blockIdx.x;

    // ---- stage 16 node rows, split fp32 -> bf16 hi + lo (float4 loads)
    {
        const float4* xg = (const float4*)(x + (size_t)blk * TM1 * 256);
        #pragma unroll
        for (int it = 0; it < 4; ++it) {
            int e = tid + it * 256;          // 1024 float4 total
            int r = e >> 6, c4 = e & 63;
            float4 v = xg[e];
            u16x4 hv, lv;
            hv[0] = f2bf(v.x); lv[0] = f2bf(v.x - bf2f(hv[0]));
            hv[1] = f2bf(v.y); lv[1] = f2bf(v.y - bf2f(hv[1]));
            hv[2] = f2bf(v.z); lv[2] = f2bf(v.z - bf2f(hv[2]));
            hv[3] = f2bf(v.w); lv[3] = f2bf(v.w - bf2f(hv[3]));
            *(u16x4*)&bufA[r * 264 + c4 * 4] = hv;
            *(u16x4*)&bufB[r * 264 + c4 * 4] = lv;
        }
    }
    __syncthreads();   // B1: x staged

    // ---- L0: 256 -> 256  (wave w owns cols [64w, 64w+64))
    f32x4 accL0[4];
    {
        const unsigned short* Wh = gw;
        const unsigned short* Wl = gw + 65536;
        f32x4 z = {0.f, 0.f, 0.f, 0.f};
        #pragma unroll
        for (int t = 0; t < 4; ++t) accL0[t] = z;
        #pragma unroll
        for (int ks = 0; ks < 8; ++ks) {
            int k0 = ks * 32 + quad * 8;
            bf16x8 ah = *(const bf16x8*)&bufA[l15 * 264 + k0];
            bf16x8 al = *(const bf16x8*)&bufB[l15 * 264 + k0];
            bf16x8 bh[4], bl[4];
            #pragma unroll
            for (int t = 0; t < 4; ++t) {
                int n = w * 64 + t * 16 + l15;
                bh[t] = *(const bf16x8*)(Wh + (size_t)n * 256 + k0);
                bl[t] = *(const bf16x8*)(Wl + (size_t)n * 256 + k0);
            }
            #pragma unroll
            for (int t = 0; t < 4; ++t) {
                accL0[t] = __builtin_amdgcn_mfma_f32_16x16x32_bf16(ah, bh[t], accL0[t], 0, 0, 0);
                accL0[t] = __builtin_amdgcn_mfma_f32_16x16x32_bf16(al, bh[t], accL0[t], 0, 0, 0);
                accL0[t] = __builtin_amdgcn_mfma_f32_16x16x32_bf16(ah, bl[t], accL0[t], 0, 0, 0);
            }
        }
    }
    __syncthreads();   // B2: all xh/xl reads done; A/B reusable

    // ---- L0 epilogue: write hh/hl into A/B
    {
        #pragma unroll
        for (int t = 0; t < 4; ++t) {
            int col = w * 64 + t * 16 + l15;
            float bb = bg0[col];
            #pragma unroll
            for (int r = 0; r < 4; ++r) {
                int row = quad * 4 + r;
                float v = fmaxf(accL0[t][r] + bb, 0.f);
                unsigned short h = f2bf(v);
                bufA[row * 264 + col] = h;
                bufB[row * 264 + col] = f2bf(v - bf2f(h));
            }
        }
    }
    __syncthreads();   // B3: hh/hl ready

    // ---- L1: 256 -> 128  (wave w owns cols [32w, 32w+32)) -> q1 (C)
    {
        const unsigned short* Wh = gw + 131072;
        const unsigned short* Wl = gw + 163840;
        f32x4 acc[2];
        f32x4 z = {0.f, 0.f, 0.f, 0.f};
        acc[0] = z; acc[1] = z;
        #pragma unroll
        for (int ks = 0; ks < 8; ++ks) {
            int k0 = ks * 32 + quad * 8;
            bf16x8 ah = *(const bf16x8*)&bufA[l15 * 264 + k0];
            bf16x8 al = *(const bf16x8*)&bufB[l15 * 264 + k0];
            bf16x8 bh[2], bl[2];
            #pragma unroll
            for (int t = 0; t < 2; ++t) {
                int n = w * 32 + t * 16 + l15;
                bh[t] = *(const bf16x8*)(Wh + (size_t)n * 256 + k0);
                bl[t] = *(const bf16x8*)(Wl + (size_t)n * 256 + k0);
            }
            #pragma unroll
            for (int t = 0; t < 2; ++t) {
                acc[t] = __builtin_amdgcn_mfma_f32_16x16x32_bf16(ah, bh[t], acc[t], 0, 0, 0);
                acc[t] = __builtin_amdgcn_mfma_f32_16x16x32_bf16(al, bh[t], acc[t], 0, 0, 0);
                acc[t] = __builtin_amdgcn_mfma_f32_16x16x32_bf16(ah, bl[t], acc[t], 0, 0, 0);
            }
        }
        #pragma unroll
        for (int t = 0; t < 2; ++t) {
            int col = w * 32 + t * 16 + l15;
            float bb = bg1[col];
            #pragma unroll
            for (int r = 0; r < 4; ++r) {
                int row = quad * 4 + r;
                float v = fmaxf(acc[t][r] + bb, 0.f);
                unsigned short h = f2bf(v);
                q1h[row * 136 + col] = h;
                q1l[row * 136 + col] = f2bf(v - bf2f(h));
            }
        }
    }
    __syncthreads();   // B4: q1 ready

    // ---- L2: 128 -> 64  (wave w owns cols [16w, 16w+16))
    f32x4 accL2;
    {
        const unsigned short* Wh = gw + 196608;
        const unsigned short* Wl = gw + 204800;
        f32x4 z = {0.f, 0.f, 0.f, 0.f};
        accL2 = z;
        #pragma unroll
        for (int ks = 0; ks < 4; ++ks) {
            int k0 = ks * 32 + quad * 8;
            bf16x8 ah = *(const bf16x8*)&q1h[l15 * 136 + k0];
            bf16x8 al = *(const bf16x8*)&q1l[l15 * 136 + k0];
            int n = w * 16 + l15;
            bf16x8 bh = *(const bf16x8*)(Wh + (size_t)n * 128 + k0);
            bf16x8 bl = *(const bf16x8*)(Wl + (size_t)n * 128 + k0);
            accL2 = __builtin_amdgcn_mfma_f32_16x16x32_bf16(ah, bh, accL2, 0, 0, 0);
            accL2 = __builtin_amdgcn_mfma_f32_16x16x32_bf16(al, bh, accL2, 0, 0, 0);
            accL2 = __builtin_amdgcn_mfma_f32_16x16x32_bf16(ah, bl, accL2, 0, 0, 0);
        }
    }
    __syncthreads();   // B5: all q1 reads done; C reusable

    // ---- L2 epilogue: g2 into C
    {
        int col = w * 16 + l15;
        float bb = bg2[col];
        #pragma unroll
        for (int r = 0; r < 4; ++r) {
            int row = quad * 4 + r;
            g2[row * 64 + col] = fmaxf(accL2[r] + bb, 0.f);
        }
    }
    __syncthreads();   // B6: g2 ready

    // ---- feats -> ws as bf16
    {
        const float* src = g2 + tid * 4;
        u16x4 p;
        p[0] = f2bf(src[0]); p[1] = f2bf(src[1]);
        p[2] = f2bf(src[2]); p[3] = f2bf(src[3]);
        *(u16x4*)&feats_bf[(size_t)blk * (TM1 * 64) + tid * 4] = p;
    }

    // ---- decoder head: 16 nodes x 24 outputs, fp32
    for (int tt = tid; tt < TM1 * 24; tt += 256) {
        int m = tt / 24;
        int c = tt - m * 24;
        float acc = bdec[c];
        for (int i = 0; i < 64; ++i) acc += g2[m * 64 + i] * Wdec[i * 24 + c];
        out_rel[(size_t)blk * (TM1 * 24) + tt] = acc;
    }

    // ---- cluster ids (as float): 128 point rows per block
    if (tid < TM1 * 8) {
        out_cluster[(size_t)blk * (TM1 * 8) + tid] = (float)(blk * TM1 + (tid >> 3));
    }
}

// ---------------------------------------------------------------------------
// Kernel 2: per-point MLP via bf16 MFMA, rank-3 fused concat
// 16 nodes = 128 rows/block, 512 threads (8 waves: 2 row-grp x 4 col-grp)
// LDS 68.5 KB -> 2 blocks/CU (16 waves/CU)
// All MFMA loops fully unrolled with 2-deep weight-register rotation so
// iteration ks+1's L2 loads overlap iteration ks's MFMAs.
// ---------------------------------------------------------------------------
__global__ __launch_bounds__(512, 4) void k_points(
    const float* __restrict__ x,
    const unsigned short* __restrict__ feats_bf,
    const float* __restrict__ rel_in,
    const unsigned short* __restrict__ wbf,
    const float* __restrict__ W0f,       // fp32 W0, rows 320..322 (rel cols)
    const float* __restrict__ b0,
    const float* __restrict__ b1,
    const float* __restrict__ b2,
    float* __restrict__ out_dec)
{
    __shared__ __attribute__((aligned(16))) unsigned char smem[70144];
    unsigned char*  hB   = smem;
    unsigned short* xcat = (unsigned short*)smem;             // [16][336]
    float*          sp   = (float*)(smem + 49152);            // [16][256]
    float*          w3   = (float*)(smem + 65536);            // [3][256]
    float*          rl   = (float*)(smem + 68608);            // [16][24]

    const int tid  = threadIdx.x;
    const int lane = tid & 63;
    const int w    = tid >> 6;      // wave id 0..7
    const int wr   = w >> 2;        // row group 0..1 (64 rows)
    const int wc   = w & 3;         // col group 0..3 (64 cols)
    const int quad = lane >> 4;
    const int l15  = lane & 15;
    const int blk  = blockIdx.x;
    const size_t nb = (size_t)blk * PNODES;

    // ---- P0: stage x (bf16), feats (bf16 copy), w3, rl
    {
        const float4* xg = (const float4*)(x + nb * 256);
        #pragma unroll
        for (int it = 0; it < 2; ++it) {
            int e = tid + it * 512;          // 1024 float4 total
            int r = e >> 6, c4 = e & 63;
            float4 v = xg[e];
            u16x4 hv;
            hv[0] = f2bf(v.x); hv[1] = f2bf(v.y);
            hv[2] = f2bf(v.z); hv[3] = f2bf(v.w);
            *(u16x4*)&xcat[r * 336 + c4 * 4] = hv;
        }
        {   // feats: 1024 u16 = 512 u32, one per thread
            int e = tid * 2;
            int r = e >> 6, c = e & 63;
            *(unsigned int*)&xcat[r * 336 + 256 + c] =
                *(const unsigned int*)&feats_bf[nb * 64 + e];
        }
        for (int e = tid; e < 768; e += 512)
            w3[e] = W0f[(size_t)(320 + (e >> 8)) * 256 + (e & 255)];
        if (tid < 384) rl[tid] = rel_in[nb * 24 + tid];
    }
    __syncthreads();   // B1

    // ---- P1: point L0: [16 x 320] @ W0t -> sp (pre-relu, pre-rel, +bias)
    {
        const unsigned short* W0t = wbf;                    // [256 n][320 k]
        f32x4 acc[2];
        f32x4 z = {0.f, 0.f, 0.f, 0.f};
        acc[0] = z; acc[1] = z;
        bf16x8 bcur[2], bnxt[2];
        #pragma unroll
        for (int t = 0; t < 2; ++t)
            bcur[t] = *(const bf16x8*)(W0t + (size_t)(w * 32 + t * 16 + l15) * 320 + quad * 8);
        #pragma unroll
        for (int ks = 0; ks < 10; ++ks) {
            int k0 = ks * 32 + quad * 8;
            bf16x8 a = *(const bf16x8*)&xcat[l15 * 336 + k0];
            if (ks < 9) {
                #pragma unroll
                for (int t = 0; t < 2; ++t)
                    bnxt[t] = *(const bf16x8*)(W0t + (size_t)(w * 32 + t * 16 + l15) * 320 + k0 + 32);
            }
            #pragma unroll
            for (int t = 0; t < 2; ++t)
                acc[t] = __builtin_amdgcn_mfma_f32_16x16x32_bf16(a, bcur[t], acc[t], 0, 0, 0);
            if (ks < 9) {
                #pragma unroll
                for (int t = 0; t < 2; ++t) bcur[t] = bnxt[t];
            }
        }
        #pragma unroll
        for (int t = 0; t < 2; ++t) {
            int col = w * 32 + t * 16 + l15;
            float bb = b0[col];
            #pragma unroll
            for (int r = 0; r < 4; ++r) {
                int row = quad * 4 + r;
                sp[row * 256 + col] = acc[t][r] + bb;
            }
        }
    }
    __syncthreads();   // B2: sp complete; xcat dead

    // ---- P2: expand sp -> h[128][256] bf16 swizzled, rank-3 rel + relu
    //      wave w owns rows [16w, 16w+16) = nodes 2w, 2w+1
    {
        float4 sv0 = *(const float4*)&sp[(2 * w) * 256 + lane * 4];
        float4 sv1 = *(const float4*)&sp[(2 * w + 1) * 256 + lane * 4];
        float4 wa  = *(const float4*)&w3[lane * 4];
        float4 wb4 = *(const float4*)&w3[256 + lane * 4];
        float4 wc4 = *(const float4*)&w3[512 + lane * 4];
        __syncthreads();   // B3: all sp reads in regs; h writes may begin
        #pragma unroll
        for (int it = 0; it < 16; ++it) {
            int row  = w * 16 + it;
            int node = 2 * w + (it >> 3);
            int p    = it & 7;
            float4 sv = (it < 8) ? sv0 : sv1;
            float ra = rl[node * 24 + p * 3 + 0];
            float rb = rl[node * 24 + p * 3 + 1];
            float rc = rl[node * 24 + p * 3 + 2];
            float v0 = fmaxf(sv.x + ra * wa.x + rb * wb4.x + rc * wc4.x, 0.f);
            float v1 = fmaxf(sv.y + ra * wa.y + rb * wb4.y + rc * wc4.y, 0.f);
            float v2 = fmaxf(sv.z + ra * wa.z + rb * wb4.z + rc * wc4.z, 0.f);
            float v3 = fmaxf(sv.w + ra * wa.w + rb * wb4.w + rc * wc4.w, 0.f);
            unsigned int lo = (unsigned int)f2bf(v0) | ((unsigned int)f2bf(v1) << 16);
            unsigned int hi = (unsigned int)f2bf(v2) | ((unsigned int)f2bf(v3) << 16);
            uint2 pk; pk.x = lo; pk.y = hi;
            int byteoff = row * 512 +
                ((((lane >> 1) ^ (row & 7)) << 4) | ((lane & 1) << 3));
            *(uint2*)(hB + byteoff) = pk;
        }
    }
    __syncthreads();   // B4

    // ---- FC1: h1 = relu(h0 @ W1 + b1); h1 overwrites h0 (reg-buffered)
    {
        const unsigned short* W1t = wbf + 81920;            // [256 n][256 k]
        f32x4 acc[4][4];
        f32x4 z = {0.f, 0.f, 0.f, 0.f};
        #pragma unroll
        for (int m = 0; m < 4; ++m)
            #pragma unroll
            for (int t = 0; t < 4; ++t) acc[m][t] = z;
        bf16x8 bcur[4], bnxt[4];
        #pragma unroll
        for (int t = 0; t < 4; ++t)
            bcur[t] = *(const bf16x8*)(W1t + (size_t)(wc * 64 + t * 16 + l15) * 256 + quad * 8);
        #pragma unroll
        for (int ks = 0; ks < 8; ++ks) {
            int k0 = ks * 32 + quad * 8;
            int g  = k0 >> 3;
            bf16x8 a[4];
            #pragma unroll
            for (int m = 0; m < 4; ++m) {
                int row = wr * 64 + m * 16 + l15;
                a[m] = *(const bf16x8*)(hB + row * 512 + ((g ^ (row & 7)) << 4));
            }
            if (ks < 7) {
                #pragma unroll
                for (int t = 0; t < 4; ++t)
                    bnxt[t] = *(const bf16x8*)(W1t + (size_t)(wc * 64 + t * 16 + l15) * 256 + k0 + 32);
            }
            #pragma unroll
            for (int m = 0; m < 4; ++m)
                #pragma unroll
                for (int t = 0; t < 4; ++t)
                    acc[m][t] = __builtin_amdgcn_mfma_f32_16x16x32_bf16(a[m], bcur[t], acc[m][t], 0, 0, 0);
            if (ks < 7) {
                #pragma unroll
                for (int t = 0; t < 4; ++t) bcur[t] = bnxt[t];
            }
        }
        __syncthreads();   // B5: all h0 reads complete before overwrite
        #pragma unroll
        for (int t = 0; t < 4; ++t) {
            int col = wc * 64 + t * 16 + l15;
            float bb = b1[col];
            #pragma unroll
            for (int m = 0; m < 4; ++m) {
                #pragma unroll
                for (int r = 0; r < 4; ++r) {
                    int row = wr * 64 + m * 16 + quad * 4 + r;
                    int byteoff = row * 512 +
                        ((((col >> 3) ^ (row & 7)) << 4) | ((col & 7) << 1));
                    *(unsigned short*)(hB + byteoff) =
                        f2bf(fmaxf(acc[m][t][r] + bb, 0.f));
                }
            }
        }
    }
    __syncthreads();   // B6

    // ---- FC2: out = relu(h1 @ W2 + b2) -> global fp32
    {
        const unsigned short* W2t = wbf + 147456;
        f32x4 acc[4][4];
        f32x4 z = {0.f, 0.f, 0.f, 0.f};
        #pragma unroll
        for (int m = 0; m < 4; ++m)
            #pragma unroll
            for (int t = 0; t < 4; ++t) acc[m][t] = z;
        bf16x8 bcur[4], bnxt[4];
        #pragma unroll
        for (int t = 0; t < 4; ++t)
            bcur[t] = *(const bf16x8*)(W2t + (size_t)(wc * 64 + t * 16 + l15) * 256 + quad * 8);
        #pragma unroll
        for (int ks = 0; ks < 8; ++ks) {
            int k0 = ks * 32 + quad * 8;
            int g  = k0 >> 3;
            bf16x8 a[4];
            #pragma unroll
            for (int m = 0; m < 4; ++m) {
                int row = wr * 64 + m * 16 + l15;
                a[m] = *(const bf16x8*)(hB + row * 512 + ((g ^ (row & 7)) << 4));
            }
            if (ks < 7) {
                #pragma unroll
                for (int t = 0; t < 4; ++t)
                    bnxt[t] = *(const bf16x8*)(W2t + (size_t)(wc * 64 + t * 16 + l15) * 256 + k0 + 32);
            }
            #pragma unroll
            for (int m = 0; m < 4; ++m)
                #pragma unroll
                for (int t = 0; t < 4; ++t)
                    acc[m][t] = __builtin_amdgcn_mfma_f32_16x16x32_bf16(a[m], bcur[t], acc[m][t], 0, 0, 0);
            if (ks < 7) {
                #pragma unroll
                for (int t = 0; t < 4; ++t) bcur[t] = bnxt[t];
            }
        }
        #pragma unroll
        for (int t = 0; t < 4; ++t) {
            int col = wc * 64 + t * 16 + l15;
            float bb = b2[col];
            #pragma unroll
            for (int m = 0; m < 4; ++m) {
                #pragma unroll
                for (int r = 0; r < 4; ++r) {
                    int row = wr * 64 + m * 16 + quad * 4 + r;
                    out_dec[((size_t)blk * 128 + row) * 256 + col] =
                        fmaxf(acc[m][t][r] + bb, 0.f);
                }
            }
        }
    }
}

// ---------------------------------------------------------------------------
extern "C" void kernel_launch(void* const* d_in, const int* in_sizes, int n_in,
                              void* d_out, int out_size, void* d_ws, size_t ws_size,
                              hipStream_t stream) {
    const float* x    = (const float*)d_in[0];
    const float* Wg0  = (const float*)d_in[1];
    const float* bg0  = (const float*)d_in[2];
    const float* Wg1  = (const float*)d_in[3];
    const float* bg1  = (const float*)d_in[4];
    const float* Wg2  = (const float*)d_in[5];
    const float* bg2  = (const float*)d_in[6];
    const float* Wdec = (const float*)d_in[7];
    const float* bdec = (const float*)d_in[8];
    const float* W0   = (const float*)d_in[9];
    const float* b0   = (const float*)d_in[10];
    const float* W1   = (const float*)d_in[11];
    const float* b1   = (const float*)d_in[12];
    const float* W2   = (const float*)d_in[13];
    const float* b2   = (const float*)d_in[14];

    float* out      = (float*)d_out;
    float* out_rel  = out;                         // [400000, 3]
    float* out_dec  = out + 1200000;               // [400000, 256]
    float* out_clu  = out + 103600000;             // [400000] as float

    unsigned short* wbf      = (unsigned short*)d_ws;
    unsigned short* feats_bf = wbf + FEATS_OFF;    // [50000, 64] bf16
    unsigned short* gw       = wbf + GW_OFF;       // split global weights

    k_prep<<<1248, 256, 0, stream>>>(W0, W1, W2, Wg0, Wg1, Wg2, wbf);
    k_global<<<NN / TM1, 256, 0, stream>>>(x, bg0, bg1, bg2, Wdec, bdec, gw,
                                           feats_bf, out_rel, out_clu);
    k_points<<<NN / PNODES, 512, 0, stream>>>(x, feats_bf, out_rel,
                                              wbf, W0, b0, b1, b2, out_dec);
}